// Round 19
// baseline (177.978 us; speedup 1.0000x reference)
//
#include <hip/hip_runtime.h>

#define N_NODES 100000
#define N_EDGES 1600000
#define IN_F 64
#define HID 128
#define HID2 64
#define NCLS 10

// slice-sorted padded CSR: 96 slots/node (Σceil4(cnt_p) ≤ d+24, d≤45 → ≤69;
// 96 gives margin and is a multiple of 16)
#define SEG 96
#define SEGI4 (SEG / 4)
#define NSLICE 8
#define SLICE 12500                    // nodes per source slice (rows: 1.6MB bf16)

// two-level binning: 256 sub-buckets of 391 nodes
#define NBUCK 256
#define SUBR 391                       // ceil(100000/256)
#define CAP2 7000                      // mean 6250, ~9.5 sigma margin
#define EBA 6250                       // edges per binA block (256 blocks)

#define ZROW N_NODES                   // zero-row index (pads contribute 0)

typedef __attribute__((ext_vector_type(8))) short bfrag;
typedef __attribute__((ext_vector_type(4))) float f32x4;

// ---- RNE float->bf16 ----
__device__ __forceinline__ unsigned short bf_rne(float f) {
  unsigned int u = __float_as_uint(f);
  u += 0x7fffu + ((u >> 16) & 1u);
  return (unsigned short)(u >> 16);
}

// ---------------- cast x -> bf16 (8 floats / thread) ----------------
__global__ __launch_bounds__(256) void cast_k(const float* __restrict__ x,
                                              unsigned short* __restrict__ xb) {
  int i = blockIdx.x * blockDim.x + threadIdx.x;   // 8-float unit
  const float4* xf4 = (const float4*)x;
  float4 a = xf4[2 * i];
  float4 b = xf4[2 * i + 1];
  ushort4 o0, o1;
  o0.x = bf_rne(a.x); o0.y = bf_rne(a.y); o0.z = bf_rne(a.z); o0.w = bf_rne(a.w);
  o1.x = bf_rne(b.x); o1.y = bf_rne(b.y); o1.z = bf_rne(b.z); o1.w = bf_rne(b.w);
  ushort4* ob = (ushort4*)xb;
  ob[2 * i] = o0;
  ob[2 * i + 1] = o1;
}

// ---- zero rows (index ZROW) for both gather tables ----
__global__ void zr_k(unsigned short* __restrict__ xb,
                     unsigned short* __restrict__ g) {
  int t = threadIdx.x;                 // 64 threads
  xb[(size_t)ZROW * IN_F + t] = 0;
  g[(size_t)ZROW * HID2 + t] = 0;
}

// ------- W1/W2 -> bf16 transposed [out][k] (once); also zeroes bcnt -------
__global__ __launch_bounds__(256) void wtrans_k(const float* __restrict__ W1,
                                                const float* __restrict__ W2,
                                                unsigned short* __restrict__ W1t,
                                                unsigned short* __restrict__ W2t,
                                                int* __restrict__ bcnt) {
  int i = blockIdx.x * 256 + threadIdx.x;          // 0 .. 16383
  if (blockIdx.x == 0) bcnt[threadIdx.x] = 0;      // NBUCK == 256
  if (i < IN_F * HID) {                            // W1t[j][k] = W1[k][j]
    int j = i >> 6, k = i & 63;                    // j<128, k<64
    W1t[i] = bf_rne(W1[k * HID + j]);
  } else {
    int i2 = i - IN_F * HID;                       // W2t[j][k] = W2[k][j]
    int j = i2 >> 7, k = i2 & 127;                 // j<64, k<128
    W2t[i2] = bf_rne(W2[k * HID2 + j]);
  }
}

// ---- binA: bin edges into 256 buckets as packed (local<<17|src) u32 ----
__global__ __launch_bounds__(256) void binA_k(const int* __restrict__ row,
                                              const int* __restrict__ col,
                                              int* __restrict__ bcnt,
                                              unsigned int* __restrict__ pairs) {
  __shared__ int hcnt[NBUCK];
  __shared__ int hbase[NBUCK];
  int t = threadIdx.x;
  hcnt[t] = 0;
  __syncthreads();
  int e0 = blockIdx.x * EBA;
  int e1 = e0 + EBA;
  for (int e = e0 + t; e < e1; e += 256) {
    int b = col[e] / SUBR;
    atomicAdd(&hcnt[b], 1);
  }
  __syncthreads();
  hbase[t] = atomicAdd(&bcnt[t], hcnt[t]);
  hcnt[t] = 0;
  __syncthreads();
  for (int e = e0 + t; e < e1; e += 256) {
    int dst = col[e];
    int src = row[e];
    int b = dst / SUBR;
    int pos = hbase[b] + atomicAdd(&hcnt[b], 1);
    pairs[(size_t)b * CAP2 + pos] =
        ((unsigned)(dst - b * SUBR) << 17) | (unsigned)src;
  }
}

// ---- binB: slice-sorted padded CSR build ----
// Per bucket (391 nodes): (1) count per-(node,slice); (2) per node compute
// 4-aligned group offsets (fallback: unpadded if >SEG), ZR-prefill all T
// slots, publish meta = d | (T<<16); (3) re-stream pairs placing each edge
// in its slice group. Pads stay ZR -> contribute exact zeros in gather.
__global__ __launch_bounds__(512) void binB_k(const unsigned int* __restrict__ pairs,
                                              const int* __restrict__ bcnt,
                                              int* __restrict__ meta,
                                              int* __restrict__ csr_src) {
  __shared__ int cnt[SUBR][NSLICE];   // 12.5 KB
  __shared__ int cur[SUBR][NSLICE];   // 12.5 KB
  int b = blockIdx.x;
  int t = threadIdx.x;
  int lo = b * SUBR;
  for (int i = t; i < SUBR * NSLICE; i += 512) ((int*)cnt)[i] = 0;
  __syncthreads();
  int cntB = bcnt[b];
  const unsigned int* bp = pairs + (size_t)b * CAP2;
  for (int i = t; i < cntB; i += 512) {
    unsigned w = bp[i];
    int local = w >> 17;
    int src = (int)(w & 0x1ffffu);
    atomicAdd(&cnt[local][src / SLICE], 1);
  }
  __syncthreads();
  // phase 2: per-node offsets + ZR prefill + meta
  for (int n = t; n < SUBR; n += 512) {
    int gn = lo + n;
    if (gn >= N_NODES) continue;
    int c[NSLICE];
    int d = 0, Tp = 0;
    for (int p = 0; p < NSLICE; p++) {
      c[p] = cnt[n][p];
      d += c[p];
      Tp += (c[p] + 3) & ~3;
    }
    int T;
    int s = 0;
    if (Tp <= SEG) {                   // padded 4-aligned groups
      for (int p = 0; p < NSLICE; p++) {
        cur[n][p] = s;
        s += (c[p] + 3) & ~3;
      }
      T = (Tp + 15) & ~15;             // ≤ SEG (96 is a mult of 16)
    } else {                           // fallback: contiguous, end-padded
      for (int p = 0; p < NSLICE; p++) {
        cur[n][p] = s;
        s += c[p];
      }
      int dc = d > SEG ? SEG : d;
      T = (dc + 15) & ~15;
    }
    meta[gn] = d | (T << 16);
    int base = gn * SEG;
    for (int q = 0; q < T; q++) csr_src[base + q] = ZROW;
  }
  __syncthreads();
  // phase 3: place edges (capacity exact per group; guard for degenerate)
  for (int i = t; i < cntB; i += 512) {
    unsigned w = bp[i];
    int local = w >> 17;
    int src = (int)(w & 0x1ffffu);
    int pos = atomicAdd(&cur[local][src / SLICE], 1);
    if (pos < SEG) csr_src[(size_t)(lo + local) * SEG + pos] = src;
  }
}

// ---------- slice-ordered bf16 gather: flat chunks of 16 slots ----------
// T is a multiple of 16; pads = ZROW (zeros). Lane = eg(0..3) x fc(0..15);
// per chunk: 1 int4 index load + 4 uint2 row loads per lane. Slice-sorted
// order keeps the live row working set ~2 slices (~3MB) -> L2-resident.
__device__ __forceinline__ float4 gather_node(const uint2* __restrict__ vb,
                                              const int4* __restrict__ csr4,
                                              int n, int T, int eg, int fc) {
  float ax = 0.f, ay = 0.f, az = 0.f, aw = 0.f;
  int b4 = n * SEGI4;
#define ACC1(r)                                                     \
  {                                                                 \
    ax += __uint_as_float((r).x << 16);                             \
    ay += __uint_as_float((r).x & 0xffff0000u);                     \
    az += __uint_as_float((r).y << 16);                             \
    aw += __uint_as_float((r).y & 0xffff0000u);                     \
  }
  for (int c = 0; c < T; c += 16) {
    int4 iu = csr4[b4 + (c >> 2) + eg];
    uint2 r0 = vb[(size_t)(unsigned)iu.x * 16 + fc];
    uint2 r1 = vb[(size_t)(unsigned)iu.y * 16 + fc];
    uint2 r2 = vb[(size_t)(unsigned)iu.z * 16 + fc];
    uint2 r3 = vb[(size_t)(unsigned)iu.w * 16 + fc];
    ACC1(r0) ACC1(r1) ACC1(r2) ACC1(r3)
  }
#undef ACC1
  ax += __shfl_xor(ax, 16); ay += __shfl_xor(ay, 16);
  az += __shfl_xor(az, 16); aw += __shfl_xor(aw, 16);
  ax += __shfl_xor(ax, 32); ay += __shfl_xor(ay, 32);
  az += __shfl_xor(az, 32); aw += __shfl_xor(aw, 32);
  return make_float4(ax, ay, az, aw);
}

// ---------- gather1: xm[n] = bf16(mean of xb rows) ----------
__global__ __launch_bounds__(256) void gather1_k(
    const unsigned short* __restrict__ xb, const int* __restrict__ meta,
    const int* __restrict__ csr_src, unsigned short* __restrict__ xm) {
  int t = threadIdx.x;
  int lane = t & 63;
  int eg = lane >> 4;
  int fc = lane & 15;
  int n0 = (blockIdx.x * 4 + (t >> 6)) * 4;
  const uint2* vb = (const uint2*)xb;
  const int4* csr4 = (const int4*)csr_src;
  for (int i = 0; i < 4; i++) {
    int n = n0 + i;
    int m = meta[n];
    int d = m & 0xffff;
    int T = m >> 16;
    float4 a = gather_node(vb, csr4, n, T, eg, fc);
    if (eg == 0) {
      float inv = 1.0f / (d < 1 ? 1.0f : (float)d);
      ushort4 o;
      o.x = bf_rne(a.x * inv); o.y = bf_rne(a.y * inv);
      o.z = bf_rne(a.z * inv); o.w = bf_rne(a.w * inv);
      *(ushort4*)&xm[(size_t)n * IN_F + fc * 4] = o;
    }
  }
}

// ---------- gather2: hm[n] = bf16(relu(mean of g rows + b2)) ----------
__global__ __launch_bounds__(256) void gather2_k(
    const unsigned short* __restrict__ g, const int* __restrict__ meta,
    const int* __restrict__ csr_src, const float* __restrict__ b2,
    unsigned short* __restrict__ hm) {
  int t = threadIdx.x;
  int lane = t & 63;
  int eg = lane >> 4;
  int fc = lane & 15;
  int n0 = (blockIdx.x * 4 + (t >> 6)) * 4;
  const uint2* vb = (const uint2*)g;
  const int4* csr4 = (const int4*)csr_src;
  const float4* b2f4 = (const float4*)b2;
  float4 bb = b2f4[fc];
  for (int i = 0; i < 4; i++) {
    int n = n0 + i;
    int m = meta[n];
    int d = m & 0xffff;
    int T = m >> 16;
    float4 a = gather_node(vb, csr4, n, T, eg, fc);
    if (eg == 0) {
      float inv = 1.0f / (d < 1 ? 1.0f : (float)d);
      float vx = a.x * inv + bb.x;
      float vy = a.y * inv + bb.y;
      float vz = a.z * inv + bb.z;
      float vw = a.w * inv + bb.w;
      ushort4 o;
      o.x = bf_rne(vx > 0.0f ? vx : 0.0f);
      o.y = bf_rne(vy > 0.0f ? vy : 0.0f);
      o.z = bf_rne(vz > 0.0f ? vz : 0.0f);
      o.w = bf_rne(vw > 0.0f ? vw : 0.0f);
      *(ushort4*)&hm[(size_t)n * HID2 + fc * 4] = o;
    }
  }
}

// ---------- mm12: dense MFMA, g = bf16(relu(xm@W1+b1) @ W2) ----------
#define NB1 32
#define XS_S 72
#define HS_S 136
__global__ __launch_bounds__(512) void mm12_k(
    const unsigned short* __restrict__ xm, const unsigned short* __restrict__ W1t,
    const float* __restrict__ b1, const unsigned short* __restrict__ W2t,
    unsigned short* __restrict__ g) {
  __shared__ unsigned short xsb[NB1 * XS_S];    // 4.5 KB
  __shared__ unsigned short hsb[NB1 * HS_S];    // 8.5 KB
  int t = threadIdx.x;
  int node0 = blockIdx.x * NB1;
  {
    int r = t >> 4, u = t & 15;
    *(ushort4*)&xsb[r * XS_S + u * 4] =
        ((const ushort4*)xm)[(size_t)(node0 + r) * (IN_F / 4) + u];
  }
  __syncthreads();
  int wave = t >> 6;
  int lane = t & 63;
  int lr = lane & 15;
  int kb = lane >> 4;
  {
    int col = wave * 16 + lr;
    bfrag wf0 = *(const bfrag*)&W1t[col * IN_F + kb * 8];
    bfrag wf1 = *(const bfrag*)&W1t[col * IN_F + 32 + kb * 8];
    float bb = b1[col];
#pragma unroll
    for (int m = 0; m < 2; m++) {
      f32x4 acc = {0.f, 0.f, 0.f, 0.f};
      bfrag a0 = *(const bfrag*)&xsb[(m * 16 + lr) * XS_S + kb * 8];
      bfrag a1 = *(const bfrag*)&xsb[(m * 16 + lr) * XS_S + 32 + kb * 8];
      acc = __builtin_amdgcn_mfma_f32_16x16x32_bf16(a0, wf0, acc, 0, 0, 0);
      acc = __builtin_amdgcn_mfma_f32_16x16x32_bf16(a1, wf1, acc, 0, 0, 0);
#pragma unroll
      for (int q = 0; q < 4; q++) {
        int r = m * 16 + kb * 4 + q;
        float v = acc[q] + bb;
        hsb[r * HS_S + col] = bf_rne(v > 0.0f ? v : 0.0f);
      }
    }
  }
  __syncthreads();
  {
    int m = wave >> 2;
    int col = (wave & 3) * 16 + lr;
    f32x4 acc = {0.f, 0.f, 0.f, 0.f};
#pragma unroll
    for (int s = 0; s < 4; s++) {
      bfrag af = *(const bfrag*)&hsb[(m * 16 + lr) * HS_S + s * 32 + kb * 8];
      bfrag bf = *(const bfrag*)&W2t[col * HID + s * 32 + kb * 8];
      acc = __builtin_amdgcn_mfma_f32_16x16x32_bf16(af, bf, acc, 0, 0, 0);
    }
#pragma unroll
    for (int q = 0; q < 4; q++) {
      int r = m * 16 + kb * 4 + q;
      g[(size_t)(node0 + r) * HID2 + col] = bf_rne(acc[q]);
    }
  }
}

// ---------- head: out = hm @ W3 + b3 ----------
#define NBH3 25
__global__ __launch_bounds__(256) void head_k(
    const unsigned short* __restrict__ hm, const float* __restrict__ W3,
    const float* __restrict__ b3, float* __restrict__ out) {
  __shared__ float W3l[HID2 * NCLS];       // 2.5 KB
  __shared__ float hsl[NBH3][HID2 + 4];    // 6.8 KB
  int t = threadIdx.x;
  for (int i = t; i < HID2 * NCLS; i += 256) W3l[i] = W3[i];
  int node0 = blockIdx.x * NBH3;
  for (int u = t; u < NBH3 * (HID2 / 4); u += 256) {
    int r = u >> 4, c = u & 15;
    ushort4 v = ((const ushort4*)hm)[(size_t)(node0 + r) * (HID2 / 4) + c];
    hsl[r][c * 4 + 0] = __uint_as_float((unsigned)v.x << 16);
    hsl[r][c * 4 + 1] = __uint_as_float((unsigned)v.y << 16);
    hsl[r][c * 4 + 2] = __uint_as_float((unsigned)v.z << 16);
    hsl[r][c * 4 + 3] = __uint_as_float((unsigned)v.w << 16);
  }
  __syncthreads();
  if (t < NBH3 * NCLS) {
    int n = t / NCLS;
    int c = t - n * NCLS;
    float a = b3[c];
    for (int k = 0; k < HID2; k++) a += hsl[n][k] * W3l[k * NCLS + c];
    out[(size_t)(node0 + n) * NCLS + c] = a;
  }
}

extern "C" void kernel_launch(void* const* d_in, const int* in_sizes, int n_in,
                              void* d_out, int out_size, void* d_ws, size_t ws_size,
                              hipStream_t stream) {
  const float* x  = (const float*)d_in[0];
  const int*   ei = (const int*)d_in[1];
  const int*   row = ei;
  const int*   col = ei + N_EDGES;
  const float* W1 = (const float*)d_in[3];
  const float* b1 = (const float*)d_in[4];
  const float* W2 = (const float*)d_in[5];
  const float* b2 = (const float*)d_in[6];
  const float* W3 = (const float*)d_in[7];
  const float* b3 = (const float*)d_in[8];
  float* out = (float*)d_out;

  char* ws = (char*)d_ws;
  int*            meta    = (int*)ws;                            // 400 KB
  int*            bcnt    = (int*)(ws + (512 << 10));            // 1 KB
  unsigned short* W1t     = (unsigned short*)(ws + (520 << 10)); // 16 KB
  unsigned short* W2t     = (unsigned short*)(ws + (552 << 10)); // 16 KB
  int*            csr_src = (int*)(ws + (1 << 20));              // 38.4 MB
  unsigned int*   pairs   = (unsigned int*)(ws + (40 << 20));    // 7.2 MB
  unsigned short* xb      = (unsigned short*)(ws + (48 << 20));  // 12.8 MB + ZR
  unsigned short* g       = (unsigned short*)(ws + (62 << 20));  // 12.8 MB + ZR
  unsigned short* xm      = (unsigned short*)(ws + (76 << 20));  // 12.8 MB
  unsigned short* hm      = xm;  // aliased: xm dead after mm12_k

  // ---- prep: W transpose (+bcnt zero) + bf16 cast + zero rows + CSR ----
  wtrans_k<<<(IN_F * HID + HID * HID2) / 256, 256, 0, stream>>>(W1, W2, W1t, W2t, bcnt);
  cast_k<<<N_NODES * IN_F / 8 / 256, 256, 0, stream>>>(x, xb);
  zr_k<<<1, 64, 0, stream>>>(xb, g);
  binA_k<<<N_EDGES / EBA, 256, 0, stream>>>(row, col, bcnt, pairs);
  binB_k<<<NBUCK, 512, 0, stream>>>(pairs, bcnt, meta, csr_src);

  // ---- layer 1: slice-local gather -> dense MFMA transform ----
  gather1_k<<<N_NODES / 16, 256, 0, stream>>>(xb, meta, csr_src, xm);
  mm12_k<<<N_NODES / NB1, 512, 0, stream>>>(xm, W1t, b1, W2t, g);

  // ---- layer 2: slice-local gather -> head ----
  gather2_k<<<N_NODES / 16, 256, 0, stream>>>(g, meta, csr_src, b2, hm);
  head_k<<<N_NODES / NBH3, 256, 0, stream>>>(hm, W3, b3, out);
}